// Round 14
// baseline (241.558 us; speedup 1.0000x reference)
//
#include <hip/hip_runtime.h>

constexpr int NN  = 20000;   // nodes
constexpr int NE  = 160000;  // edges (= 625*256)
constexpr int CAP = 32;      // per-node bucket capacity (deg ~ Poisson(8), max ~21)
constexpr int NBM = 16;      // blocks in MLP kernel

// ---- agent-scope (cross-XCD safe) scalar access --------------------------
__device__ inline void gstore(float* p, float v) {
    __hip_atomic_store(p, v, __ATOMIC_RELAXED, __HIP_MEMORY_SCOPE_AGENT);
}
__device__ inline float gload(const float* p) {
    return __hip_atomic_load(p, __ATOMIC_RELAXED, __HIP_MEMORY_SCOPE_AGENT);
}

// inter-block barrier: monotonic counter, arrive then (optionally) spin.
// NOTE (R10 lesson): single-counter barrier is only viable for O(10) blocks.
__device__ inline void mbarrier(int* ctr, int target, bool wait) {
    __syncthreads();
    if (threadIdx.x == 0) {
        __threadfence();
        __hip_atomic_fetch_add(ctr, 1, __ATOMIC_ACQ_REL, __HIP_MEMORY_SCOPE_AGENT);
        if (wait)
            while (__hip_atomic_load(ctr, __ATOMIC_ACQUIRE, __HIP_MEMORY_SCOPE_AGENT) < target) {}
    }
    __syncthreads();
}

// ---------------------------------------------------------------------------
// Stage W columns [c0, c0+CH) into LDS. s<8 = We, s==8 = be, s==9 = root.
// ---------------------------------------------------------------------------
template<int FI, int FO2, int CH>
__device__ void stage_half(float* Wh, const float* __restrict__ We,
                           const float* __restrict__ be, const float* __restrict__ root,
                           int c0)
{
    constexpr int O4 = FO2 / 4;
    for (int t = threadIdx.x; t < FI * CH; t += 256) {
        const int f = t / CH, ccp = t % CH, cc = c0 + ccp;
        const int s = cc / O4, oq = cc % O4;
        const float4* src;
        if (s < 8)       src = (const float4*)(We + (size_t)s * FI * FO2 + f * FO2 + oq * 4);
        else if (s == 8) src = (const float4*)(be + f * FO2 + oq * 4);
        else             src = (const float4*)(root + f * FO2 + oq * 4);
        ((float4*)Wh)[t] = *src;
    }
}

// ---------------------------------------------------------------------------
// GEMM columns [c0,c0+CH): segs 0..8 -> P_lds (stride 9*FO2); seg9+bias -> g.
// TNB = nodes per block.
// ---------------------------------------------------------------------------
template<int FI, int FO2, int CH, int TNB>
__device__ void gemm_PL(const float* htile, const float* Wh,
                        const float* __restrict__ bias,
                        float* P_lds, float* __restrict__ seg9g, int n0, int c0)
{
    constexpr int O4 = FO2 / 4, PL = 9 * FO2;
    constexpr int TPN = 256 / TNB;
    constexpr int HS  = FI + 4;
    const int nl = threadIdx.x / TPN, lane = threadIdx.x % TPN;
    const float*  hr = &htile[nl * HS];
    const float4* W4 = (const float4*)Wh;
    for (int ccp = lane; ccp < CH; ccp += TPN) {
        const int cc = c0 + ccp;
        float4 a = {0.f, 0.f, 0.f, 0.f};
        #pragma unroll
        for (int f = 0; f < FI; f++) {
            const float  hf = hr[f];
            const float4 w  = W4[f * CH + ccp];
            a.x = fmaf(hf, w.x, a.x); a.y = fmaf(hf, w.y, a.y);
            a.z = fmaf(hf, w.z, a.z); a.w = fmaf(hf, w.w, a.w);
        }
        if (cc < 9 * O4) {
            *(float4*)&P_lds[nl * PL + cc * 4] = a;
        } else {
            const float4 b4 = ((const float4*)bias)[cc - 9 * O4];
            a.x += b4.x; a.y += b4.y; a.z += b4.z; a.w += b4.w;
            *(float4*)&seg9g[(size_t)(n0 + nl) * FO2 + (cc - 9 * O4) * 4] = a;
        }
    }
}

// ---------------------------------------------------------------------------
// Push compute: slot -> eid (sequential, wave-deduped) -> e row (scattered
// 32B READ of hot 5.1MB array — reads don't RMW, unlike the old esort
// scattered WRITES in bucket). msg writes stay sequential per bucket.
// ---------------------------------------------------------------------------
template<int FO2, int TNB>
__device__ void push_direct(const float* P_lds, const int* offs_s,
                            const int* __restrict__ se_eid, const float* __restrict__ e,
                            float* __restrict__ msg, int n0)
{
    constexpr int PL = 9 * FO2, OQ2 = FO2 / 4;
    const int ET = offs_s[TNB];
    for (int T = threadIdx.x; T < ET * OQ2; T += 256) {
        const int ed = T / OQ2, oq = T % OQ2;
        int nl = 0;
        #pragma unroll
        for (int i = 1; i < TNB; i++) nl += (ed >= offs_s[i]);
        const int slot = (n0 + nl) * CAP + (ed - offs_s[nl]);
        const int eid  = se_eid[slot];
        const float4 e0 = *(const float4*)(e + (size_t)eid * 8);
        const float4 e1 = *(const float4*)(e + (size_t)eid * 8 + 4);
        const float* Pr = &P_lds[nl * PL + oq * 4];
        float4 m = *(const float4*)(Pr + 8 * FO2);
        float4 w;
        w = *(const float4*)(Pr + 0 * FO2);
        m.x = fmaf(e0.x, w.x, m.x); m.y = fmaf(e0.x, w.y, m.y);
        m.z = fmaf(e0.x, w.z, m.z); m.w = fmaf(e0.x, w.w, m.w);
        w = *(const float4*)(Pr + 1 * FO2);
        m.x = fmaf(e0.y, w.x, m.x); m.y = fmaf(e0.y, w.y, m.y);
        m.z = fmaf(e0.y, w.z, m.z); m.w = fmaf(e0.y, w.w, m.w);
        w = *(const float4*)(Pr + 2 * FO2);
        m.x = fmaf(e0.z, w.x, m.x); m.y = fmaf(e0.z, w.y, m.y);
        m.z = fmaf(e0.z, w.z, m.z); m.w = fmaf(e0.z, w.w, m.w);
        w = *(const float4*)(Pr + 3 * FO2);
        m.x = fmaf(e0.w, w.x, m.x); m.y = fmaf(e0.w, w.y, m.y);
        m.z = fmaf(e0.w, w.z, m.z); m.w = fmaf(e0.w, w.w, m.w);
        w = *(const float4*)(Pr + 4 * FO2);
        m.x = fmaf(e1.x, w.x, m.x); m.y = fmaf(e1.x, w.y, m.y);
        m.z = fmaf(e1.x, w.z, m.z); m.w = fmaf(e1.x, w.w, m.w);
        w = *(const float4*)(Pr + 5 * FO2);
        m.x = fmaf(e1.y, w.x, m.x); m.y = fmaf(e1.y, w.y, m.y);
        m.z = fmaf(e1.y, w.z, m.z); m.w = fmaf(e1.y, w.w, m.w);
        w = *(const float4*)(Pr + 6 * FO2);
        m.x = fmaf(e1.z, w.x, m.x); m.y = fmaf(e1.z, w.y, m.y);
        m.z = fmaf(e1.z, w.z, m.z); m.w = fmaf(e1.z, w.w, m.w);
        w = *(const float4*)(Pr + 7 * FO2);
        m.x = fmaf(e1.w, w.x, m.x); m.y = fmaf(e1.w, w.y, m.y);
        m.z = fmaf(e1.w, w.z, m.z); m.w = fmaf(e1.w, w.w, m.w);
        *(float4*)&msg[(size_t)slot * FO2 + oq * 4] = m;
    }
}

// ---------------------------------------------------------------------------
// D2: dual buckets. src bucket stores eid only (4B scattered writes — the
// 20.5MB esort 32B-granule write-scatter is GONE); tgt bucket records the
// src slot for gather indirection.
// ---------------------------------------------------------------------------
__global__ __launch_bounds__(256)
void bucket_kernel(const int* __restrict__ eidx,
                   int* __restrict__ cnt_s, int* __restrict__ cnt_t,
                   int* __restrict__ se_eid, int* __restrict__ te_slot)
{
    const int eid = blockIdx.x * 256 + threadIdx.x;    // NE == 625*256
    const int2 st = ((const int2*)eidx)[eid];
    const int qs = atomicAdd(&cnt_s[st.x], 1);
    if (qs < CAP) {
        const int slot = st.x * CAP + qs;
        se_eid[slot] = eid;
        const int qt = atomicAdd(&cnt_t[st.y], 1);
        if (qt < CAP) te_slot[st.y * CAP + qt] = slot;
    }
}

// ---------------------------------------------------------------------------
// D3: layer 1 — x tile -> P1(LDS segs0..8, seg9->global) -> msg1.
// FI=16, FO2=40, 2 W passes (CH=50), TNB=8, ~25 KB LDS -> 6 blocks/CU.
// ---------------------------------------------------------------------------
__global__ __launch_bounds__(256, 6)
void l1_push_kernel(const float* __restrict__ x,
                    const float* __restrict__ We1, const float* __restrict__ be1,
                    const float* __restrict__ root1, const float* __restrict__ b1,
                    const int* __restrict__ cnt_s, const int* __restrict__ se_eid,
                    const float* __restrict__ e,
                    float* __restrict__ seg9_1, float* __restrict__ msg1)
{
    constexpr int FI = 16, FO2 = 40, CH = 50, TNB = 8;
    __shared__ float Wh[FI * CH * 4];        // 3200 f
    __shared__ float P_lds[TNB * 9 * FO2];   // 2880 f
    __shared__ float htile[TNB * (FI + 4)];  // 160 f
    __shared__ int   offs_s[TNB + 1];
    const int tid = threadIdx.x;
    const int n0  = blockIdx.x * TNB;        // grid 2500

    if (tid == 0) {
        int a = 0;
        for (int i = 0; i < TNB; i++) { offs_s[i] = a; a += min(cnt_s[n0 + i], CAP); }
        offs_s[TNB] = a;
    }
    stage_half<FI, FO2, CH>(Wh, We1, be1, root1, 0);
    for (int t = tid; t < TNB * 4; t += 256) {
        const int nl = t / 4, fq = t % 4;
        *(float4*)&htile[nl * 20 + fq * 4] =
            *(const float4*)(x + (size_t)(n0 + nl) * 16 + fq * 4);
    }
    __syncthreads();
    gemm_PL<FI, FO2, CH, TNB>(htile, Wh, b1, P_lds, seg9_1, n0, 0);
    __syncthreads();
    stage_half<FI, FO2, CH>(Wh, We1, be1, root1, CH);
    __syncthreads();
    gemm_PL<FI, FO2, CH, TNB>(htile, Wh, b1, P_lds, seg9_1, n0, CH);
    __syncthreads();
    push_direct<FO2, TNB>(P_lds, offs_s, se_eid, e, msg1, n0);
}

// ---------------------------------------------------------------------------
// D4/D5: fused gather (deep-batched) -> relu -> GEMM -> push (eid-indirect).
// TNB=16 nodes/block (grid 1250). D4 uses CHP=20 (3 W passes) so LDS fits
// 5 blocks/CU on the latency-bound gather/push phases.
// ---------------------------------------------------------------------------
template<int FI, int FO2, int CHP, int TNB, int MINB>
__global__ __launch_bounds__(256, MINB)
void gather_gemm_push_kernel(const float* __restrict__ msg_prev,
                             const int* __restrict__ cnt_t, const int* __restrict__ te_slot,
                             const float* __restrict__ seg9_prev,
                             const float* __restrict__ We, const float* __restrict__ be,
                             const float* __restrict__ root, const float* __restrict__ bias,
                             const int* __restrict__ cnt_s, const int* __restrict__ se_eid,
                             const float* __restrict__ e,
                             float* __restrict__ seg9_next, float* __restrict__ msg_next)
{
    constexpr int C4    = 10 * FO2 / 4;
    constexpr int NPASS = C4 / CHP;
    constexpr int OQi   = FI / 4, HS = FI + 4;
    __shared__ float Wh[FI * CHP * 4];
    __shared__ float P_lds[TNB * 9 * FO2];
    __shared__ float htile[TNB * HS];
    __shared__ int   tslot[TNB * CAP];
    __shared__ int   offs_s[TNB + 1];
    const int tid = threadIdx.x;
    const int n0  = blockIdx.x * TNB;

    if (tid == 0) {
        int a = 0;
        for (int i = 0; i < TNB; i++) { offs_s[i] = a; a += min(cnt_s[n0 + i], CAP); }
        offs_s[TNB] = a;
    }
    for (int t = tid; t < TNB * CAP; t += 256) {
        const int nl = t / CAP, k = t % CAP;
        const int dd = min(cnt_t[n0 + nl], CAP);
        tslot[t] = (k < dd) ? te_slot[n0 * CAP + t] : -1;
    }
    stage_half<FI, FO2, CHP>(Wh, We, be, root, 0);
    __syncthreads();

    // deep-batched gather: one thread per (node, oq); 8 loads in flight;
    // seg9 init + relu folded in (exclusive ownership of the htile slot).
    for (int T = tid; T < TNB * OQi; T += 256) {
        const int nl = T / OQi, oq = T % OQi;
        const int d = min(cnt_t[n0 + nl], CAP);
        float4 acc = *(const float4*)(seg9_prev + (size_t)(n0 + nl) * FI + oq * 4);
        const int* ts = &tslot[nl * CAP];
        for (int k0 = 0; k0 < CAP; k0 += 8) {
            if (k0 >= d) break;
            int sl[8]; float4 v[8];
            #pragma unroll
            for (int u = 0; u < 8; u++) {
                sl[u] = ts[k0 + u];
                const int sc = sl[u] < 0 ? 0 : sl[u];
                v[u] = *(const float4*)(msg_prev + (size_t)sc * FI + oq * 4);
            }
            #pragma unroll
            for (int u = 0; u < 8; u++) {
                if (sl[u] >= 0) {
                    acc.x += v[u].x; acc.y += v[u].y;
                    acc.z += v[u].z; acc.w += v[u].w;
                }
            }
        }
        acc.x = fmaxf(acc.x, 0.f); acc.y = fmaxf(acc.y, 0.f);
        acc.z = fmaxf(acc.z, 0.f); acc.w = fmaxf(acc.w, 0.f);
        *(float4*)&htile[nl * HS + oq * 4] = acc;
    }
    __syncthreads();

    gemm_PL<FI, FO2, CHP, TNB>(htile, Wh, bias, P_lds, seg9_next, n0, 0);
    #pragma unroll
    for (int p = 1; p < NPASS; p++) {
        __syncthreads();
        stage_half<FI, FO2, CHP>(Wh, We, be, root, p * CHP);
        __syncthreads();
        gemm_PL<FI, FO2, CHP, TNB>(htile, Wh, bias, P_lds, seg9_next, n0, p * CHP);
    }
    __syncthreads();
    push_direct<FO2, TNB>(P_lds, offs_s, se_eid, e, msg_next, n0);
}

// ---------------------------------------------------------------------------
// D6: deep-batched gather of msg3 + seg9_3, relu, colsum -> g (24-wide).
// TNB=32, grid 625: 192/256 gather-active threads, half the block tail.
// ---------------------------------------------------------------------------
__global__ __launch_bounds__(256)
void msg_colsum_kernel(const float* __restrict__ msg, const int* __restrict__ cnt_t,
                       const int* __restrict__ te_slot, const float* __restrict__ seg9,
                       float* __restrict__ g)
{
    constexpr int FO = 24, OQ = 6, TNB = 32;
    __shared__ int tslot[TNB * CAP];
    __shared__ float gl[FO];
    const int tid = threadIdx.x;
    const int n0  = blockIdx.x * TNB;

    if (tid < FO) gl[tid] = 0.f;
    for (int t = tid; t < TNB * CAP; t += 256) {
        const int nl = t / CAP, k = t % CAP;
        const int dd = min(cnt_t[n0 + nl], CAP);
        tslot[t] = (k < dd) ? te_slot[n0 * CAP + t] : -1;
    }
    __syncthreads();

    for (int T = tid; T < TNB * OQ; T += 256) {
        const int nl = T / OQ, oq = T % OQ;
        const int d = min(cnt_t[n0 + nl], CAP);
        float4 acc = *(const float4*)(seg9 + (size_t)(n0 + nl) * FO + oq * 4);
        const int* ts = &tslot[nl * CAP];
        for (int k0 = 0; k0 < CAP; k0 += 8) {
            if (k0 >= d) break;
            int sl[8]; float4 v[8];
            #pragma unroll
            for (int u = 0; u < 8; u++) {
                sl[u] = ts[k0 + u];
                const int sc = sl[u] < 0 ? 0 : sl[u];
                v[u] = *(const float4*)(msg + (size_t)sc * FO + oq * 4);
            }
            #pragma unroll
            for (int u = 0; u < 8; u++) {
                if (sl[u] >= 0) {
                    acc.x += v[u].x; acc.y += v[u].y;
                    acc.z += v[u].z; acc.w += v[u].w;
                }
            }
        }
        atomicAdd(&gl[oq * 4 + 0], fmaxf(acc.x, 0.f));
        atomicAdd(&gl[oq * 4 + 1], fmaxf(acc.y, 0.f));
        atomicAdd(&gl[oq * 4 + 2], fmaxf(acc.z, 0.f));
        atomicAdd(&gl[oq * 4 + 3], fmaxf(acc.w, 0.f));
    }
    __syncthreads();
    if (tid < FO) unsafeAtomicAdd(&g[tid], gl[tid]);
}

// ---------------------------------------------------------------------------
// D7: MLP head, 16 blocks, 2 inter-block barriers (NBM-scale only).
// ---------------------------------------------------------------------------
__global__ __launch_bounds__(256)
void mlp_kernel(const float* __restrict__ g, int* __restrict__ ctr,
                const float* __restrict__ Wd1, const float* __restrict__ bd1,
                const float* __restrict__ Wd2, const float* __restrict__ bd2,
                const float* __restrict__ Wd3, const float* __restrict__ bd3,
                const float* __restrict__ Wd4, const float* __restrict__ bd4,
                const float* __restrict__ Wd5, const float* __restrict__ bd5,
                const float* __restrict__ Wd6, const float* __restrict__ bd6,
                float* __restrict__ m3, float* __restrict__ m4,
                float* __restrict__ out)
{
    __shared__ float v0[768];
    __shared__ float v1[96];
    __shared__ float red[256];
    const int tid = threadIdx.x, b = blockIdx.x;

    if (tid < 24) v0[tid] = g[tid];
    __syncthreads();
    if (tid < 96) {
        float a = bd1[tid];
        #pragma unroll
        for (int i = 0; i < 24; i++) a = fmaf(v0[i], Wd1[i * 96 + tid], a);
        v1[tid] = fmaxf(a, 0.f);
    }
    __syncthreads();
    {
        float a = bd2[tid];
        #pragma unroll
        for (int i = 0; i < 96; i++) a = fmaf(v1[i], Wd2[i * 256 + tid], a);
        red[tid] = fmaxf(a, 0.f);
    }
    __syncthreads();
    v0[tid] = red[tid];
    __syncthreads();

    if (tid < 192) {
        const int o = b * 48 + (tid % 48), kg = tid / 48;
        float a = 0.f;
        #pragma unroll 8
        for (int i = kg * 64; i < kg * 64 + 64; i++)
            a = fmaf(v0[i], Wd3[(size_t)i * 768 + o], a);
        red[tid] = a;
    }
    __syncthreads();
    if (tid < 48) {
        float s = bd3[b * 48 + tid] + red[tid] + red[48 + tid] + red[96 + tid] + red[144 + tid];
        gstore(&m3[b * 48 + tid], fmaxf(s, 0.f));
    }
    mbarrier(ctr, 1 * NBM, true);

    for (int i = tid; i < 768; i += 256) v0[i] = gload(&m3[i]);
    __syncthreads();
    {
        const int o = b * 32 + (tid & 31), kg = tid >> 5;
        float a = 0.f;
        #pragma unroll 8
        for (int i = kg * 96; i < kg * 96 + 96; i++)
            a = fmaf(v0[i], Wd4[(size_t)i * 512 + o], a);
        red[tid] = a;
    }
    __syncthreads();
    if (tid < 32) {
        float s = bd4[b * 32 + tid];
        #pragma unroll
        for (int k = 0; k < 8; k++) s += red[k * 32 + tid];
        gstore(&m4[b * 32 + tid], fmaxf(s, 0.f));
    }
    mbarrier(ctr, 2 * NBM, b == 0);

    if (b == 0) {
        for (int i = tid; i < 512; i += 256) v0[i] = gload(&m4[i]);
        __syncthreads();
        {
            const int o = tid & 63, kg = tid >> 6;
            float a = 0.f;
            #pragma unroll 8
            for (int i = kg * 128; i < kg * 128 + 128; i++)
                a = fmaf(v0[i], Wd5[(size_t)i * 64 + o], a);
            red[tid] = a;
        }
        __syncthreads();
        if (tid < 64) {
            float s = bd5[tid] + red[tid] + red[64 + tid] + red[128 + tid] + red[192 + tid];
            float v = fmaxf(s, 0.f) * Wd6[tid];
            #pragma unroll
            for (int off = 32; off > 0; off >>= 1)
                v += __shfl_down(v, off, 64);
            if (tid == 0) out[0] = v + bd6[0];
        }
    }
}

// ---------------------------------------------------------------------------
extern "C" void kernel_launch(void* const* d_in, const int* in_sizes, int n_in,
                              void* d_out, int out_size, void* d_ws, size_t ws_size,
                              hipStream_t stream)
{
    const float* x     = (const float*)d_in[0];
    const int*   eidx  = (const int*)  d_in[1];
    const float* e     = (const float*)d_in[2];
    const float* We1   = (const float*)d_in[3];  const float* be1 = (const float*)d_in[4];
    const float* root1 = (const float*)d_in[5];  const float* b1  = (const float*)d_in[6];
    const float* We2   = (const float*)d_in[7];  const float* be2 = (const float*)d_in[8];
    const float* root2 = (const float*)d_in[9];  const float* b2  = (const float*)d_in[10];
    const float* We3   = (const float*)d_in[11]; const float* be3 = (const float*)d_in[12];
    const float* root3 = (const float*)d_in[13]; const float* b3  = (const float*)d_in[14];
    const float* Wd1 = (const float*)d_in[15]; const float* bd1 = (const float*)d_in[16];
    const float* Wd2 = (const float*)d_in[17]; const float* bd2 = (const float*)d_in[18];
    const float* Wd3 = (const float*)d_in[19]; const float* bd3 = (const float*)d_in[20];
    const float* Wd4 = (const float*)d_in[21]; const float* bd4 = (const float*)d_in[22];
    const float* Wd5 = (const float*)d_in[23]; const float* bd5 = (const float*)d_in[24];
    const float* Wd6 = (const float*)d_in[25]; const float* bd6 = (const float*)d_in[26];

    // ---- workspace layout (4-byte units) ----
    int*   wi      = (int*)d_ws;
    float* wf      = (float*)d_ws;
    int*   cnt_s   = wi;                       //         0 ..    20000
    int*   cnt_t   = wi + 20000;               //     20000 ..    40000
    float* g       = wf + 40000;               //     24
    int*   mctr    = wi + 40064;               //     own 64B line
    float* m3      = wf + 40096;               //     768
    float* m4      = m3 + 768;                 //     512   (ends 41376)
    int*   te_slot = wi + 41376;               //     640,000 ->   681,376
    int*   se_eid  = wi + 681376;              //     640,000 -> 1,321,376
    float* seg9_1  = wf + 1321376;             //     800,000 -> 2,121,376
    float* seg9_2  = wf + 2121376;             //     480,000 -> 2,601,376
    float* seg9_3  = wf + 2601376;             //     480,000 -> 3,081,376
    float* msg1    = wf + 3081376;             //     25,600,000 -> 28,681,376
    float* msg3    = msg1;                     //     msg1 dead before msg3 written
    float* msg2    = wf + 28681376;            //     15,360,000 -> 44,041,376
    // total ~44.0M floats ~= 176 MB

    // D1: zero cnt_s + cnt_t + g + mctr + m3/m4 (165 KB)
    hipMemsetAsync(d_ws, 0, (size_t)41376 * sizeof(float), stream);

    // D2: dual buckets (eid only — no e-row materialization)
    bucket_kernel<<<625, 256, 0, stream>>>(eidx, cnt_s, cnt_t, se_eid, te_slot);

    // D3: layer 1 — x -> P1(LDS) -> msg1 + seg9_1   (TNB=8, grid 2500)
    l1_push_kernel<<<NN / 8, 256, 0, stream>>>(x, We1, be1, root1, b1,
                                               cnt_s, se_eid, e, seg9_1, msg1);

    // D4: gather msg1 -> h1 -> P2(LDS) -> msg2 + seg9_2  (TNB=16, CHP=20, 5 blk/CU)
    gather_gemm_push_kernel<40, 24, 20, 16, 5><<<NN / 16, 256, 0, stream>>>(
        msg1, cnt_t, te_slot, seg9_1, We2, be2, root2, b2,
        cnt_s, se_eid, e, seg9_2, msg2);

    // D5: gather msg2 -> h2 -> P3(LDS) -> msg3 + seg9_3  (TNB=16, CHP=30, 5 blk/CU)
    gather_gemm_push_kernel<24, 24, 30, 16, 5><<<NN / 16, 256, 0, stream>>>(
        msg2, cnt_t, te_slot, seg9_2, We3, be3, root3, b3,
        cnt_s, se_eid, e, seg9_3, msg3);

    // D6: g = colsum(relu(msg3-sum + seg9_3))   (TNB=32, grid 625)
    msg_colsum_kernel<<<NN / 32, 256, 0, stream>>>(msg3, cnt_t, te_slot, seg9_3, g);

    // D7: MLP head (16 blocks, 2 internal barriers)
    mlp_kernel<<<NBM, 256, 0, stream>>>(g, mctr,
                                        Wd1, bd1, Wd2, bd2, Wd3, bd3,
                                        Wd4, bd4, Wd5, bd5, Wd6, bd6,
                                        m3, m4, (float*)d_out);
}

// Round 15
// 236.508 us; speedup vs baseline: 1.0214x; 1.0214x over previous
//
#include <hip/hip_runtime.h>

constexpr int NN  = 20000;   // nodes
constexpr int NE  = 160000;  // edges (= 625*256)
constexpr int CAP = 32;      // per-node bucket capacity (deg ~ Poisson(8), max ~21)
constexpr int NBM = 16;      // blocks in MLP kernel

// ---- agent-scope (cross-XCD safe) scalar access --------------------------
__device__ inline void gstore(float* p, float v) {
    __hip_atomic_store(p, v, __ATOMIC_RELAXED, __HIP_MEMORY_SCOPE_AGENT);
}
__device__ inline float gload(const float* p) {
    return __hip_atomic_load(p, __ATOMIC_RELAXED, __HIP_MEMORY_SCOPE_AGENT);
}

// inter-block barrier: monotonic counter, arrive then (optionally) spin.
// NOTE (R10 lesson): single-counter barrier is only viable for O(10) blocks.
__device__ inline void mbarrier(int* ctr, int target, bool wait) {
    __syncthreads();
    if (threadIdx.x == 0) {
        __threadfence();
        __hip_atomic_fetch_add(ctr, 1, __ATOMIC_ACQ_REL, __HIP_MEMORY_SCOPE_AGENT);
        if (wait)
            while (__hip_atomic_load(ctr, __ATOMIC_ACQUIRE, __HIP_MEMORY_SCOPE_AGENT) < target) {}
    }
    __syncthreads();
}

// ---------------------------------------------------------------------------
// Stage W columns [c0, c0+CH) into LDS. s<8 = We, s==8 = be, s==9 = root.
// ---------------------------------------------------------------------------
template<int FI, int FO2, int CH>
__device__ void stage_half(float* Wh, const float* __restrict__ We,
                           const float* __restrict__ be, const float* __restrict__ root,
                           int c0)
{
    constexpr int O4 = FO2 / 4;
    for (int t = threadIdx.x; t < FI * CH; t += 256) {
        const int f = t / CH, ccp = t % CH, cc = c0 + ccp;
        const int s = cc / O4, oq = cc % O4;
        const float4* src;
        if (s < 8)       src = (const float4*)(We + (size_t)s * FI * FO2 + f * FO2 + oq * 4);
        else if (s == 8) src = (const float4*)(be + f * FO2 + oq * 4);
        else             src = (const float4*)(root + f * FO2 + oq * 4);
        ((float4*)Wh)[t] = *src;
    }
}

// ---------------------------------------------------------------------------
// GEMM columns [c0,c0+CH): segs 0..8 -> P_lds (stride 9*FO2); seg9+bias -> g.
// TNB = nodes per block.
// ---------------------------------------------------------------------------
template<int FI, int FO2, int CH, int TNB>
__device__ void gemm_PL(const float* htile, const float* Wh,
                        const float* __restrict__ bias,
                        float* P_lds, float* __restrict__ seg9g, int n0, int c0)
{
    constexpr int O4 = FO2 / 4, PL = 9 * FO2;
    constexpr int TPN = 256 / TNB;
    constexpr int HS  = FI + 4;
    const int nl = threadIdx.x / TPN, lane = threadIdx.x % TPN;
    const float*  hr = &htile[nl * HS];
    const float4* W4 = (const float4*)Wh;
    for (int ccp = lane; ccp < CH; ccp += TPN) {
        const int cc = c0 + ccp;
        float4 a = {0.f, 0.f, 0.f, 0.f};
        #pragma unroll
        for (int f = 0; f < FI; f++) {
            const float  hf = hr[f];
            const float4 w  = W4[f * CH + ccp];
            a.x = fmaf(hf, w.x, a.x); a.y = fmaf(hf, w.y, a.y);
            a.z = fmaf(hf, w.z, a.z); a.w = fmaf(hf, w.w, a.w);
        }
        if (cc < 9 * O4) {
            *(float4*)&P_lds[nl * PL + cc * 4] = a;
        } else {
            const float4 b4 = ((const float4*)bias)[cc - 9 * O4];
            a.x += b4.x; a.y += b4.y; a.z += b4.z; a.w += b4.w;
            *(float4*)&seg9g[(size_t)(n0 + nl) * FO2 + (cc - 9 * O4) * 4] = a;
        }
    }
}

// ---------------------------------------------------------------------------
// Push compute reading esort DIRECTLY (saves LDS; consecutive threads share
// the same e-row lines, so the wave coalescer dedups; L2-hot).
// ---------------------------------------------------------------------------
template<int FO2, int TNB>
__device__ void push_direct(const float* P_lds, const int* offs_s,
                            const float* __restrict__ esort,
                            float* __restrict__ msg, int n0)
{
    constexpr int PL = 9 * FO2, OQ2 = FO2 / 4;
    const int ET = offs_s[TNB];
    for (int T = threadIdx.x; T < ET * OQ2; T += 256) {
        const int ed = T / OQ2, oq = T % OQ2;
        int nl = 0;
        #pragma unroll
        for (int i = 1; i < TNB; i++) nl += (ed >= offs_s[i]);
        const int slot = (n0 + nl) * CAP + (ed - offs_s[nl]);
        const float4 e0 = *(const float4*)(esort + (size_t)slot * 8);
        const float4 e1 = *(const float4*)(esort + (size_t)slot * 8 + 4);
        const float* Pr = &P_lds[nl * PL + oq * 4];
        float4 m = *(const float4*)(Pr + 8 * FO2);
        float4 w;
        w = *(const float4*)(Pr + 0 * FO2);
        m.x = fmaf(e0.x, w.x, m.x); m.y = fmaf(e0.x, w.y, m.y);
        m.z = fmaf(e0.x, w.z, m.z); m.w = fmaf(e0.x, w.w, m.w);
        w = *(const float4*)(Pr + 1 * FO2);
        m.x = fmaf(e0.y, w.x, m.x); m.y = fmaf(e0.y, w.y, m.y);
        m.z = fmaf(e0.y, w.z, m.z); m.w = fmaf(e0.y, w.w, m.w);
        w = *(const float4*)(Pr + 2 * FO2);
        m.x = fmaf(e0.z, w.x, m.x); m.y = fmaf(e0.z, w.y, m.y);
        m.z = fmaf(e0.z, w.z, m.z); m.w = fmaf(e0.z, w.w, m.w);
        w = *(const float4*)(Pr + 3 * FO2);
        m.x = fmaf(e0.w, w.x, m.x); m.y = fmaf(e0.w, w.y, m.y);
        m.z = fmaf(e0.w, w.z, m.z); m.w = fmaf(e0.w, w.w, m.w);
        w = *(const float4*)(Pr + 4 * FO2);
        m.x = fmaf(e1.x, w.x, m.x); m.y = fmaf(e1.x, w.y, m.y);
        m.z = fmaf(e1.x, w.z, m.z); m.w = fmaf(e1.x, w.w, m.w);
        w = *(const float4*)(Pr + 5 * FO2);
        m.x = fmaf(e1.y, w.x, m.x); m.y = fmaf(e1.y, w.y, m.y);
        m.z = fmaf(e1.y, w.z, m.z); m.w = fmaf(e1.y, w.w, m.w);
        w = *(const float4*)(Pr + 6 * FO2);
        m.x = fmaf(e1.z, w.x, m.x); m.y = fmaf(e1.z, w.y, m.y);
        m.z = fmaf(e1.z, w.z, m.z); m.w = fmaf(e1.z, w.w, m.w);
        w = *(const float4*)(Pr + 7 * FO2);
        m.x = fmaf(e1.w, w.x, m.x); m.y = fmaf(e1.w, w.y, m.y);
        m.z = fmaf(e1.w, w.z, m.z); m.w = fmaf(e1.w, w.w, m.w);
        *(float4*)&msg[(size_t)slot * FO2 + oq * 4] = m;
    }
}

// ---------------------------------------------------------------------------
// D2: dual buckets. src bucket gets e-row materialized in slot order (esort);
// tgt bucket records the src slot for gather indirection.
// ---------------------------------------------------------------------------
__global__ __launch_bounds__(256)
void bucket_kernel(const int* __restrict__ eidx, const float* __restrict__ e,
                   int* __restrict__ cnt_s, int* __restrict__ cnt_t,
                   int* __restrict__ te_slot, float* __restrict__ esort)
{
    const int eid = blockIdx.x * 256 + threadIdx.x;    // NE == 625*256
    const int2 st = ((const int2*)eidx)[eid];
    const int qs = atomicAdd(&cnt_s[st.x], 1);
    if (qs < CAP) {
        const int slot = st.x * CAP + qs;
        const float4* e4 = (const float4*)(e + (size_t)eid * 8);
        *(float4*)&esort[(size_t)slot * 8]     = e4[0];
        *(float4*)&esort[(size_t)slot * 8 + 4] = e4[1];
        const int qt = atomicAdd(&cnt_t[st.y], 1);
        if (qt < CAP) te_slot[st.y * CAP + qt] = slot;
    }
}

// ---------------------------------------------------------------------------
// D3: layer 1 — x tile -> P1(LDS segs0..8, seg9->global) -> msg1.
// FI=16, FO2=40, 2 W passes (CH=50), TNB=8, ~25 KB LDS -> 6 blocks/CU.
// ---------------------------------------------------------------------------
__global__ __launch_bounds__(256, 6)
void l1_push_kernel(const float* __restrict__ x,
                    const float* __restrict__ We1, const float* __restrict__ be1,
                    const float* __restrict__ root1, const float* __restrict__ b1,
                    const int* __restrict__ cnt_s, const float* __restrict__ esort,
                    float* __restrict__ seg9_1, float* __restrict__ msg1)
{
    constexpr int FI = 16, FO2 = 40, CH = 50, TNB = 8;
    __shared__ float Wh[FI * CH * 4];        // 3200 f
    __shared__ float P_lds[TNB * 9 * FO2];   // 2880 f
    __shared__ float htile[TNB * (FI + 4)];  // 160 f
    __shared__ int   offs_s[TNB + 1];
    const int tid = threadIdx.x;
    const int n0  = blockIdx.x * TNB;        // grid 2500

    if (tid == 0) {
        int a = 0;
        for (int i = 0; i < TNB; i++) { offs_s[i] = a; a += min(cnt_s[n0 + i], CAP); }
        offs_s[TNB] = a;
    }
    stage_half<FI, FO2, CH>(Wh, We1, be1, root1, 0);
    for (int t = tid; t < TNB * 4; t += 256) {
        const int nl = t / 4, fq = t % 4;
        *(float4*)&htile[nl * 20 + fq * 4] =
            *(const float4*)(x + (size_t)(n0 + nl) * 16 + fq * 4);
    }
    __syncthreads();
    gemm_PL<FI, FO2, CH, TNB>(htile, Wh, b1, P_lds, seg9_1, n0, 0);
    __syncthreads();
    stage_half<FI, FO2, CH>(Wh, We1, be1, root1, CH);
    __syncthreads();
    gemm_PL<FI, FO2, CH, TNB>(htile, Wh, b1, P_lds, seg9_1, n0, CH);
    __syncthreads();
    push_direct<FO2, TNB>(P_lds, offs_s, esort, msg1, n0);
}

// ---------------------------------------------------------------------------
// D4/D5: fused gather (deep-batched) -> relu -> GEMM -> push (direct esort).
// TNB=16 nodes/block (grid 1250). D4 uses CHP=20 (3 W passes) so LDS fits
// 5 blocks/CU on the latency-bound gather/push phases.
// ---------------------------------------------------------------------------
template<int FI, int FO2, int CHP, int TNB, int MINB>
__global__ __launch_bounds__(256, MINB)
void gather_gemm_push_kernel(const float* __restrict__ msg_prev,
                             const int* __restrict__ cnt_t, const int* __restrict__ te_slot,
                             const float* __restrict__ seg9_prev,
                             const float* __restrict__ We, const float* __restrict__ be,
                             const float* __restrict__ root, const float* __restrict__ bias,
                             const int* __restrict__ cnt_s, const float* __restrict__ esort,
                             float* __restrict__ seg9_next, float* __restrict__ msg_next)
{
    constexpr int C4    = 10 * FO2 / 4;
    constexpr int NPASS = C4 / CHP;
    constexpr int OQi   = FI / 4, HS = FI + 4;
    __shared__ float Wh[FI * CHP * 4];
    __shared__ float P_lds[TNB * 9 * FO2];
    __shared__ float htile[TNB * HS];
    __shared__ int   tslot[TNB * CAP];
    __shared__ int   offs_s[TNB + 1];
    const int tid = threadIdx.x;
    const int n0  = blockIdx.x * TNB;

    if (tid == 0) {
        int a = 0;
        for (int i = 0; i < TNB; i++) { offs_s[i] = a; a += min(cnt_s[n0 + i], CAP); }
        offs_s[TNB] = a;
    }
    for (int t = tid; t < TNB * CAP; t += 256) {
        const int nl = t / CAP, k = t % CAP;
        const int dd = min(cnt_t[n0 + nl], CAP);
        tslot[t] = (k < dd) ? te_slot[n0 * CAP + t] : -1;
    }
    stage_half<FI, FO2, CHP>(Wh, We, be, root, 0);
    __syncthreads();

    // deep-batched gather: one thread per (node, oq); 8 loads in flight;
    // seg9 init + relu folded in (exclusive ownership of the htile slot).
    for (int T = tid; T < TNB * OQi; T += 256) {
        const int nl = T / OQi, oq = T % OQi;
        const int d = min(cnt_t[n0 + nl], CAP);
        float4 acc = *(const float4*)(seg9_prev + (size_t)(n0 + nl) * FI + oq * 4);
        const int* ts = &tslot[nl * CAP];
        for (int k0 = 0; k0 < CAP; k0 += 8) {
            if (k0 >= d) break;
            int sl[8]; float4 v[8];
            #pragma unroll
            for (int u = 0; u < 8; u++) {
                sl[u] = ts[k0 + u];
                const int sc = sl[u] < 0 ? 0 : sl[u];
                v[u] = *(const float4*)(msg_prev + (size_t)sc * FI + oq * 4);
            }
            #pragma unroll
            for (int u = 0; u < 8; u++) {
                if (sl[u] >= 0) {
                    acc.x += v[u].x; acc.y += v[u].y;
                    acc.z += v[u].z; acc.w += v[u].w;
                }
            }
        }
        acc.x = fmaxf(acc.x, 0.f); acc.y = fmaxf(acc.y, 0.f);
        acc.z = fmaxf(acc.z, 0.f); acc.w = fmaxf(acc.w, 0.f);
        *(float4*)&htile[nl * HS + oq * 4] = acc;
    }
    __syncthreads();

    gemm_PL<FI, FO2, CHP, TNB>(htile, Wh, bias, P_lds, seg9_next, n0, 0);
    #pragma unroll
    for (int p = 1; p < NPASS; p++) {
        __syncthreads();
        stage_half<FI, FO2, CHP>(Wh, We, be, root, p * CHP);
        __syncthreads();
        gemm_PL<FI, FO2, CHP, TNB>(htile, Wh, bias, P_lds, seg9_next, n0, p * CHP);
    }
    __syncthreads();
    push_direct<FO2, TNB>(P_lds, offs_s, esort, msg_next, n0);
}

// ---------------------------------------------------------------------------
// D6: deep-batched gather of msg3 + seg9_3, relu, colsum -> g (24-wide).
// TNB=32, grid 625: 192/256 gather-active threads, half the block tail.
// ---------------------------------------------------------------------------
__global__ __launch_bounds__(256)
void msg_colsum_kernel(const float* __restrict__ msg, const int* __restrict__ cnt_t,
                       const int* __restrict__ te_slot, const float* __restrict__ seg9,
                       float* __restrict__ g)
{
    constexpr int FO = 24, OQ = 6, TNB = 32;
    __shared__ int tslot[TNB * CAP];
    __shared__ float gl[FO];
    const int tid = threadIdx.x;
    const int n0  = blockIdx.x * TNB;

    if (tid < FO) gl[tid] = 0.f;
    for (int t = tid; t < TNB * CAP; t += 256) {
        const int nl = t / CAP, k = t % CAP;
        const int dd = min(cnt_t[n0 + nl], CAP);
        tslot[t] = (k < dd) ? te_slot[n0 * CAP + t] : -1;
    }
    __syncthreads();

    for (int T = tid; T < TNB * OQ; T += 256) {
        const int nl = T / OQ, oq = T % OQ;
        const int d = min(cnt_t[n0 + nl], CAP);
        float4 acc = *(const float4*)(seg9 + (size_t)(n0 + nl) * FO + oq * 4);
        const int* ts = &tslot[nl * CAP];
        for (int k0 = 0; k0 < CAP; k0 += 8) {
            if (k0 >= d) break;
            int sl[8]; float4 v[8];
            #pragma unroll
            for (int u = 0; u < 8; u++) {
                sl[u] = ts[k0 + u];
                const int sc = sl[u] < 0 ? 0 : sl[u];
                v[u] = *(const float4*)(msg + (size_t)sc * FO + oq * 4);
            }
            #pragma unroll
            for (int u = 0; u < 8; u++) {
                if (sl[u] >= 0) {
                    acc.x += v[u].x; acc.y += v[u].y;
                    acc.z += v[u].z; acc.w += v[u].w;
                }
            }
        }
        atomicAdd(&gl[oq * 4 + 0], fmaxf(acc.x, 0.f));
        atomicAdd(&gl[oq * 4 + 1], fmaxf(acc.y, 0.f));
        atomicAdd(&gl[oq * 4 + 2], fmaxf(acc.z, 0.f));
        atomicAdd(&gl[oq * 4 + 3], fmaxf(acc.w, 0.f));
    }
    __syncthreads();
    if (tid < FO) unsafeAtomicAdd(&g[tid], gl[tid]);
}

// ---------------------------------------------------------------------------
// D7: MLP head, 16 blocks, 2 inter-block barriers (NBM-scale only).
// ---------------------------------------------------------------------------
__global__ __launch_bounds__(256)
void mlp_kernel(const float* __restrict__ g, int* __restrict__ ctr,
                const float* __restrict__ Wd1, const float* __restrict__ bd1,
                const float* __restrict__ Wd2, const float* __restrict__ bd2,
                const float* __restrict__ Wd3, const float* __restrict__ bd3,
                const float* __restrict__ Wd4, const float* __restrict__ bd4,
                const float* __restrict__ Wd5, const float* __restrict__ bd5,
                const float* __restrict__ Wd6, const float* __restrict__ bd6,
                float* __restrict__ m3, float* __restrict__ m4,
                float* __restrict__ out)
{
    __shared__ float v0[768];
    __shared__ float v1[96];
    __shared__ float red[256];
    const int tid = threadIdx.x, b = blockIdx.x;

    if (tid < 24) v0[tid] = g[tid];
    __syncthreads();
    if (tid < 96) {
        float a = bd1[tid];
        #pragma unroll
        for (int i = 0; i < 24; i++) a = fmaf(v0[i], Wd1[i * 96 + tid], a);
        v1[tid] = fmaxf(a, 0.f);
    }
    __syncthreads();
    {
        float a = bd2[tid];
        #pragma unroll
        for (int i = 0; i < 96; i++) a = fmaf(v1[i], Wd2[i * 256 + tid], a);
        red[tid] = fmaxf(a, 0.f);
    }
    __syncthreads();
    v0[tid] = red[tid];
    __syncthreads();

    if (tid < 192) {
        const int o = b * 48 + (tid % 48), kg = tid / 48;
        float a = 0.f;
        #pragma unroll 8
        for (int i = kg * 64; i < kg * 64 + 64; i++)
            a = fmaf(v0[i], Wd3[(size_t)i * 768 + o], a);
        red[tid] = a;
    }
    __syncthreads();
    if (tid < 48) {
        float s = bd3[b * 48 + tid] + red[tid] + red[48 + tid] + red[96 + tid] + red[144 + tid];
        gstore(&m3[b * 48 + tid], fmaxf(s, 0.f));
    }
    mbarrier(ctr, 1 * NBM, true);

    for (int i = tid; i < 768; i += 256) v0[i] = gload(&m3[i]);
    __syncthreads();
    {
        const int o = b * 32 + (tid & 31), kg = tid >> 5;
        float a = 0.f;
        #pragma unroll 8
        for (int i = kg * 96; i < kg * 96 + 96; i++)
            a = fmaf(v0[i], Wd4[(size_t)i * 512 + o], a);
        red[tid] = a;
    }
    __syncthreads();
    if (tid < 32) {
        float s = bd4[b * 32 + tid];
        #pragma unroll
        for (int k = 0; k < 8; k++) s += red[k * 32 + tid];
        gstore(&m4[b * 32 + tid], fmaxf(s, 0.f));
    }
    mbarrier(ctr, 2 * NBM, b == 0);

    if (b == 0) {
        for (int i = tid; i < 512; i += 256) v0[i] = gload(&m4[i]);
        __syncthreads();
        {
            const int o = tid & 63, kg = tid >> 6;
            float a = 0.f;
            #pragma unroll 8
            for (int i = kg * 128; i < kg * 128 + 128; i++)
                a = fmaf(v0[i], Wd5[(size_t)i * 64 + o], a);
            red[tid] = a;
        }
        __syncthreads();
        if (tid < 64) {
            float s = bd5[tid] + red[tid] + red[64 + tid] + red[128 + tid] + red[192 + tid];
            float v = fmaxf(s, 0.f) * Wd6[tid];
            #pragma unroll
            for (int off = 32; off > 0; off >>= 1)
                v += __shfl_down(v, off, 64);
            if (tid == 0) out[0] = v + bd6[0];
        }
    }
}

// ---------------------------------------------------------------------------
extern "C" void kernel_launch(void* const* d_in, const int* in_sizes, int n_in,
                              void* d_out, int out_size, void* d_ws, size_t ws_size,
                              hipStream_t stream)
{
    const float* x     = (const float*)d_in[0];
    const int*   eidx  = (const int*)  d_in[1];
    const float* e     = (const float*)d_in[2];
    const float* We1   = (const float*)d_in[3];  const float* be1 = (const float*)d_in[4];
    const float* root1 = (const float*)d_in[5];  const float* b1  = (const float*)d_in[6];
    const float* We2   = (const float*)d_in[7];  const float* be2 = (const float*)d_in[8];
    const float* root2 = (const float*)d_in[9];  const float* b2  = (const float*)d_in[10];
    const float* We3   = (const float*)d_in[11]; const float* be3 = (const float*)d_in[12];
    const float* root3 = (const float*)d_in[13]; const float* b3  = (const float*)d_in[14];
    const float* Wd1 = (const float*)d_in[15]; const float* bd1 = (const float*)d_in[16];
    const float* Wd2 = (const float*)d_in[17]; const float* bd2 = (const float*)d_in[18];
    const float* Wd3 = (const float*)d_in[19]; const float* bd3 = (const float*)d_in[20];
    const float* Wd4 = (const float*)d_in[21]; const float* bd4 = (const float*)d_in[22];
    const float* Wd5 = (const float*)d_in[23]; const float* bd5 = (const float*)d_in[24];
    const float* Wd6 = (const float*)d_in[25]; const float* bd6 = (const float*)d_in[26];

    // ---- workspace layout (4-byte units) ----
    int*   wi      = (int*)d_ws;
    float* wf      = (float*)d_ws;
    int*   cnt_s   = wi;                       //         0 ..    20000
    int*   cnt_t   = wi + 20000;               //     20000 ..    40000
    float* g       = wf + 40000;               //     24
    int*   mctr    = wi + 40064;               //     own 64B line
    float* m3      = wf + 40096;               //     768
    float* m4      = m3 + 768;                 //     512   (ends 41376)
    int*   te_slot = wi + 41376;               //     640,000 ->   681,376
    float* esort   = wf + 681376;              //     640,000*8 = 5,120,000 -> 5,801,376
    float* seg9_1  = wf + 5801376;             //     800,000 -> 6,601,376
    float* seg9_2  = wf + 6601376;             //     480,000 -> 7,081,376
    float* seg9_3  = wf + 7081376;             //     480,000 -> 7,561,376
    float* msg1    = wf + 7561376;             //     25,600,000 -> 33,161,376
    float* msg3    = msg1;                     //     msg1 dead before msg3 written
    float* msg2    = wf + 33161376;            //     15,360,000 -> 48,521,376
    // total ~48.5M floats ~= 194 MB

    // D1: zero cnt_s + cnt_t + g + mctr + m3/m4 (165 KB)
    hipMemsetAsync(d_ws, 0, (size_t)41376 * sizeof(float), stream);

    // D2: dual buckets + esort (e rows in src-slot order)
    bucket_kernel<<<625, 256, 0, stream>>>(eidx, e, cnt_s, cnt_t, te_slot, esort);

    // D3: layer 1 — x -> P1(LDS) -> msg1 + seg9_1   (TNB=8, grid 2500)
    l1_push_kernel<<<NN / 8, 256, 0, stream>>>(x, We1, be1, root1, b1,
                                               cnt_s, esort, seg9_1, msg1);

    // D4: gather msg1 -> h1 -> P2(LDS) -> msg2 + seg9_2  (TNB=16, CHP=20, 5 blk/CU)
    gather_gemm_push_kernel<40, 24, 20, 16, 5><<<NN / 16, 256, 0, stream>>>(
        msg1, cnt_t, te_slot, seg9_1, We2, be2, root2, b2,
        cnt_s, esort, seg9_2, msg2);

    // D5: gather msg2 -> h2 -> P3(LDS) -> msg3 + seg9_3  (TNB=16, CHP=30, 5 blk/CU)
    gather_gemm_push_kernel<24, 24, 30, 16, 5><<<NN / 16, 256, 0, stream>>>(
        msg2, cnt_t, te_slot, seg9_2, We3, be3, root3, b3,
        cnt_s, esort, seg9_3, msg3);

    // D6: g = colsum(relu(msg3-sum + seg9_3))   (TNB=32, grid 625)
    msg_colsum_kernel<<<NN / 32, 256, 0, stream>>>(msg3, cnt_t, te_slot, seg9_3, g);

    // D7: MLP head (16 blocks, 2 internal barriers)
    mlp_kernel<<<NBM, 256, 0, stream>>>(g, mctr,
                                        Wd1, bd1, Wd2, bd2, Wd3, bd3,
                                        Wd4, bd4, Wd5, bd5, Wd6, bd6,
                                        m3, m4, (float*)d_out);
}